// Round 2
// baseline (391.227 us; speedup 1.0000x reference)
//
#include <hip/hip_runtime.h>

// UWNeRF RGB renderer: R rays x S=128 samples, fp32.
// 32 lanes per ray (2 rays per wave), lane owns 4 contiguous samples.
// R3: software-pipelined streaming — each thread handles NR=4 rays and issues
// the NEXT ray's 14 global loads before computing the current ray, so memory
// requests stay outstanding during the ~900cy compute phase.
// (R2 evidence: total read traffic pinned at 3.3 TB/s = half of copy-kernel
// per-CU BW, with VALU 20% / L1 22% / HBM 26% / LDS 0 all idle => the gate is
// per-wave memory duty cycle, not any pipe. DPP scan/butterfly kept from R2.)

constexpr int S = 128;
constexpr int NR = 4;   // rays per thread (pipeline depth 1 ahead)

// x + dpp(x) with compile-time DPP control; old=0 so masked rows add identity.
template<int CTRL, int RM, bool BC>
__device__ __forceinline__ float dpp_add(float x) {
    const int t = __builtin_amdgcn_update_dpp(0, __float_as_int(x), CTRL, RM, 0xF, BC);
    return x + __int_as_float(t);
}

// x + lane(x ^ 16) via ds_swizzle (BitMode xor=16: 0x401F)
__device__ __forceinline__ float swz16_add(float x) {
    const int t = __builtin_amdgcn_ds_swizzle(__float_as_int(x), 0x401F);
    return x + __int_as_float(t);
}

struct Ray {
    float4 den, dlt;
    float4 rgb[3], vl[3], dc[3], bc[3];
};

__device__ __forceinline__ Ray load_ray(
    const float* __restrict__ densities, const float* __restrict__ rgbs,
    const float* __restrict__ veil, const float* __restrict__ dcoef,
    const float* __restrict__ bcoef, const float* __restrict__ deltas,
    int r, int l)
{
    Ray d;
    const size_t b1 = (size_t)r * S + 4 * (size_t)l;   // scalar arrays, 16B/lane
    const size_t b3 = b1 * 3;                          // channel arrays, 48B/lane
    d.den = *(const float4*)(densities + b1);
    d.dlt = *(const float4*)(deltas + b1);
#pragma unroll
    for (int i = 0; i < 3; ++i) {
        d.rgb[i] = *(const float4*)(rgbs  + b3 + 4 * i);
        d.vl[i]  = *(const float4*)(veil  + b3 + 4 * i);
        d.dc[i]  = *(const float4*)(dcoef + b3 + 4 * i);
        d.bc[i]  = *(const float4*)(bcoef + b3 + 4 * i);
    }
    return d;
}

__device__ __forceinline__ void compute_ray(const Ray& d, int r, int l,
                                            float* __restrict__ out, int R)
{
    float rgbv[12], vlv[12], dcv[12], bcv[12];
#pragma unroll
    for (int i = 0; i < 3; ++i) {
        *(float4*)(rgbv + 4 * i) = d.rgb[i];
        *(float4*)(vlv  + 4 * i) = d.vl[i];
        *(float4*)(dcv  + 4 * i) = d.dc[i];
        *(float4*)(bcv  + 4 * i) = d.bc[i];
    }
    const float dl[4] = {d.dlt.x, d.dlt.y, d.dlt.z, d.dlt.w};
    const float dn[4] = {d.den.x, d.den.y, d.den.z, d.den.w};

    // local exclusive prefixes (per-lane, in registers)
    float odd[4], cumO[4];
    float accO = 0.0f;
#pragma unroll
    for (int s = 0; s < 4; ++s) {
        odd[s] = dl[s] * dn[s];
        cumO[s] = accO;
        accO += odd[s];
    }

    float cumD[12], cumB[12], loc[7];
    loc[0] = accO;
#pragma unroll
    for (int c = 0; c < 3; ++c) {
        float ad = 0.0f, ab = 0.0f;
#pragma unroll
        for (int s = 0; s < 4; ++s) {
            const float dv = dl[s] * dcv[3 * s + c];
            const float bv = dl[s] * bcv[3 * s + c];
            cumD[4 * c + s] = ad; ad += dv;
            cumB[4 * c + s] = ab; ab += bv;
        }
        loc[1 + c] = ad;
        loc[4 + c] = ab;
    }

    // inclusive scan of 7 lane-aggregates within each 32-lane half — DPP (VALU pipe)
    float agg[7];
#pragma unroll
    for (int j = 0; j < 7; ++j) agg[j] = loc[j];
#pragma unroll
    for (int j = 0; j < 7; ++j) agg[j] = dpp_add<0x111, 0xF, true>(agg[j]);  // row_shr:1
#pragma unroll
    for (int j = 0; j < 7; ++j) agg[j] = dpp_add<0x112, 0xF, true>(agg[j]);  // row_shr:2
#pragma unroll
    for (int j = 0; j < 7; ++j) agg[j] = dpp_add<0x114, 0xF, true>(agg[j]);  // row_shr:4
#pragma unroll
    for (int j = 0; j < 7; ++j) agg[j] = dpp_add<0x118, 0xF, true>(agg[j]);  // row_shr:8
#pragma unroll
    for (int j = 0; j < 7; ++j) agg[j] = dpp_add<0x142, 0xA, false>(agg[j]); // row_bcast15

    float Lex[7];  // exclusive lane prefix
#pragma unroll
    for (int j = 0; j < 7; ++j) Lex[j] = agg[j] - loc[j];

    // object transmittance / weights
    float t_[4], T_[4], w_[4];
    const float TL = __expf(-Lex[0]);
#pragma unroll
    for (int s = 0; s < 4; ++s) t_[s] = __expf(-odd[s]);
    T_[0] = TL;
#pragma unroll
    for (int s = 1; s < 4; ++s) T_[s] = T_[s - 1] * t_[s - 1];
#pragma unroll
    for (int s = 0; s < 4; ++s) w_[s] = (1.0f - t_[s]) * T_[s];

    // partial reductions: [0..2] restored, [3..5] direct, [6..8] backscatter_obj,
    // [9] wsum, [10..12] veil[s=0] broadcast (only lane 0 contributes)
    float red[13];
    red[9] = w_[0] + w_[1] + w_[2] + w_[3];
#pragma unroll
    for (int c = 0; c < 3; ++c) {
        const float BD = Lex[0] + Lex[1 + c];
        const float BB = Lex[0] + Lex[4 + c];
        float sr = 0.0f, sd = 0.0f, sb = 0.0f;
#pragma unroll
        for (int s = 0; s < 4; ++s) {
            const float g = rgbv[3 * s + c];
            const float v = vlv[3 * s + c];
            const float omt = 1.0f - t_[s];
            const float wda = omt * __expf(-(BD + cumO[s] + cumD[4 * c + s]));
            const float wbt = omt * __expf(-(BB + cumO[s] + cumB[4 * c + s]));
            sr += w_[s] * g;
            sd += wda * g;
            sb += (w_[s] - wbt) * v;
        }
        red[c] = sr;
        red[3 + c] = sd;
        red[6 + c] = sb;
        red[10 + c] = (l == 0) ? vlv[c] : 0.0f;
    }

    // butterfly reduction within each 32-lane half — DPP + one ds_swizzle hop
#pragma unroll
    for (int j = 0; j < 13; ++j) red[j] = dpp_add<0xB1, 0xF, false>(red[j]);  // xor1
#pragma unroll
    for (int j = 0; j < 13; ++j) red[j] = dpp_add<0x4E, 0xF, false>(red[j]);  // xor2
#pragma unroll
    for (int j = 0; j < 13; ++j) red[j] = dpp_add<0x141, 0xF, false>(red[j]); // xor4 (half_mirror)
#pragma unroll
    for (int j = 0; j < 13; ++j) red[j] = dpp_add<0x140, 0xF, false>(red[j]); // xor8-equiv (mirror)
#pragma unroll
    for (int j = 0; j < 13; ++j) red[j] = swz16_add(red[j]);                  // xor16

    if (l < 3) {
        const int c = l;
        const float mask = fminf(fmaxf(red[9], 0.0f), 1.0f);
        const float bsr  = red[6 + c] + (1.0f - mask) * red[10 + c];
        const size_t rc = (size_t)r * 3 + c;
        const size_t stride = (size_t)R * 3;
        out[rc]              = fminf(fmaxf(red[3 + c] + bsr, 0.0f), 1.0f); // rgb
        out[stride + rc]     = fminf(fmaxf(red[c],          0.0f), 1.0f); // restored
        out[2 * stride + rc] = fminf(fmaxf(red[3 + c],      0.0f), 1.0f); // direct
        out[3 * stride + rc] = fminf(fmaxf(bsr,             0.0f), 1.0f); // backscatter
    }
}

__global__ __launch_bounds__(256) void uwnerf_render(
    const float* __restrict__ densities,   // [R,S,1]
    const float* __restrict__ rgbs,        // [R,S,3]
    const float* __restrict__ veil,        // [R,S,3]
    const float* __restrict__ dcoef,       // [R,S,3]
    const float* __restrict__ bcoef,       // [R,S,3]
    const float* __restrict__ deltas,      // [R,S,1]
    float* __restrict__ out,               // [4,R,3]: rgb, restored, direct, backscatter
    int R)
{
    const int lane = threadIdx.x & 63;
    const int l = lane & 31;          // lane within ray
    const int r0 = blockIdx.x * 8 + (int)(threadIdx.x >> 6) * 2 + (lane >> 5);
    const int rstride = (int)gridDim.x * 8;   // rays per sweep

    if (r0 >= R) return;

    Ray cur = load_ray(densities, rgbs, veil, dcoef, bcoef, deltas, r0, l);

#pragma unroll
    for (int it = 0; it < NR; ++it) {
        const int rc = r0 + it * rstride;
        const int rn = r0 + (it + 1) * rstride;
        Ray nxt;
        const bool have_next = (it + 1 < NR) && (rn < R);
        if (have_next)
            nxt = load_ray(densities, rgbs, veil, dcoef, bcoef, deltas, rn, l);
        if (rc < R)
            compute_ray(cur, rc, l, out, R);
        if (have_next)
            cur = nxt;   // register rename under full unroll
    }
}

extern "C" void kernel_launch(void* const* d_in, const int* in_sizes, int n_in,
                              void* d_out, int out_size, void* d_ws, size_t ws_size,
                              hipStream_t stream) {
    const float* densities = (const float*)d_in[0];
    const float* rgbs      = (const float*)d_in[1];
    const float* veil      = (const float*)d_in[2];
    const float* bcoef_    = (const float*)d_in[4];
    const float* dcoef     = (const float*)d_in[3];
    const float* deltas    = (const float*)d_in[5];
    float* out = (float*)d_out;

    const int R = in_sizes[0] / S;   // 65536
    const int rays_per_block_sweep = 8;
    const int blocks = (R + rays_per_block_sweep * NR - 1) / (rays_per_block_sweep * NR); // 2048
    dim3 grid(blocks), block(256);
    uwnerf_render<<<grid, block, 0, stream>>>(densities, rgbs, veil, dcoef, bcoef_,
                                              deltas, out, R);
}

// Round 3
// 391.060 us; speedup vs baseline: 1.0004x; 1.0004x over previous
//
#include <hip/hip_runtime.h>

// UWNeRF RGB renderer: R rays x S=128 samples, fp32.
// 32 lanes per ray (2 rays per wave), lane owns 4 contiguous samples.
// R4: TRUE software pipeline — inline-asm global_load_dwordx4 + counted
// s_waitcnt vmcnt(14) + sched_barrier(0). R3's source-level prefetch was
// compiler-defeated (VGPR=96 < 112 needed for two Ray buffers). Counted
// vmcnt keeps the next ray's 14 loads in flight across the whole compute
// phase (T4 mechanism); vmcnt(0) only at the pipeline tail.
// (Invariant being attacked: 448 MB read / 145 us = 3.09 TB/s = 5 B/cy/CU
// with nothing saturated — either per-wave memory duty cycle (fixable) or
// per-CU MSHR*latency ceiling (roofline). This kernel distinguishes them.)

constexpr int S = 128;

// x + dpp(x) with compile-time DPP control; old=0 so masked rows add identity.
template<int CTRL, int RM, bool BC>
__device__ __forceinline__ float dpp_add(float x) {
    const int t = __builtin_amdgcn_update_dpp(0, __float_as_int(x), CTRL, RM, 0xF, BC);
    return x + __int_as_float(t);
}

// x + lane(x ^ 16) via ds_swizzle (BitMode xor=16: 0x401F)
__device__ __forceinline__ float swz16_add(float x) {
    const int t = __builtin_amdgcn_ds_swizzle(__float_as_int(x), 0x401F);
    return x + __int_as_float(t);
}

struct Ray {
    float4 den, dlt;
    float4 rgb0, rgb1, rgb2;
    float4 vl0,  vl1,  vl2;
    float4 dc0,  dc1,  dc2;
    float4 bc0,  bc1,  bc2;
};

// Fire-and-forget 16B load: compiler does not track the vmcnt increment;
// completion is guaranteed only by our explicit counted s_waitcnt.
#define GLOAD(dst, ptr) \
    asm volatile("global_load_dwordx4 %0, %1, off" : "=v"(dst) : "v"(ptr))

__device__ __forceinline__ void issue_loads(Ray& d,
    const float* __restrict__ densities, const float* __restrict__ rgbs,
    const float* __restrict__ veil, const float* __restrict__ dcoef,
    const float* __restrict__ bcoef, const float* __restrict__ deltas,
    int r, int l)
{
    const size_t b1 = (size_t)r * S + 4 * (size_t)l;   // scalar arrays, 16B/lane
    const size_t b3 = b1 * 3;                          // channel arrays, 48B/lane
    GLOAD(d.den, densities + b1);
    GLOAD(d.dlt, deltas + b1);
    GLOAD(d.rgb0, rgbs + b3);  GLOAD(d.rgb1, rgbs + b3 + 4);  GLOAD(d.rgb2, rgbs + b3 + 8);
    GLOAD(d.vl0, veil + b3);   GLOAD(d.vl1, veil + b3 + 4);   GLOAD(d.vl2, veil + b3 + 8);
    GLOAD(d.dc0, dcoef + b3);  GLOAD(d.dc1, dcoef + b3 + 4);  GLOAD(d.dc2, dcoef + b3 + 8);
    GLOAD(d.bc0, bcoef + b3);  GLOAD(d.bc1, bcoef + b3 + 4);  GLOAD(d.bc2, bcoef + b3 + 8);
}

__device__ __forceinline__ void compute_ray(const Ray& d, int r, int l,
                                            float* __restrict__ out, int R)
{
    float rgbv[12], vlv[12], dcv[12], bcv[12];
    *(float4*)(rgbv + 0) = d.rgb0; *(float4*)(rgbv + 4) = d.rgb1; *(float4*)(rgbv + 8) = d.rgb2;
    *(float4*)(vlv  + 0) = d.vl0;  *(float4*)(vlv  + 4) = d.vl1;  *(float4*)(vlv  + 8) = d.vl2;
    *(float4*)(dcv  + 0) = d.dc0;  *(float4*)(dcv  + 4) = d.dc1;  *(float4*)(dcv  + 8) = d.dc2;
    *(float4*)(bcv  + 0) = d.bc0;  *(float4*)(bcv  + 4) = d.bc1;  *(float4*)(bcv  + 8) = d.bc2;

    const float dl[4] = {d.dlt.x, d.dlt.y, d.dlt.z, d.dlt.w};
    const float dn[4] = {d.den.x, d.den.y, d.den.z, d.den.w};

    // local exclusive prefixes (per-lane, in registers)
    float odd[4], cumO[4];
    float accO = 0.0f;
#pragma unroll
    for (int s = 0; s < 4; ++s) {
        odd[s] = dl[s] * dn[s];
        cumO[s] = accO;
        accO += odd[s];
    }

    float cumD[12], cumB[12], loc[7];
    loc[0] = accO;
#pragma unroll
    for (int c = 0; c < 3; ++c) {
        float ad = 0.0f, ab = 0.0f;
#pragma unroll
        for (int s = 0; s < 4; ++s) {
            const float dv = dl[s] * dcv[3 * s + c];
            const float bv = dl[s] * bcv[3 * s + c];
            cumD[4 * c + s] = ad; ad += dv;
            cumB[4 * c + s] = ab; ab += bv;
        }
        loc[1 + c] = ad;
        loc[4 + c] = ab;
    }

    // inclusive scan of 7 lane-aggregates within each 32-lane half — DPP (VALU pipe)
    float agg[7];
#pragma unroll
    for (int j = 0; j < 7; ++j) agg[j] = loc[j];
#pragma unroll
    for (int j = 0; j < 7; ++j) agg[j] = dpp_add<0x111, 0xF, true>(agg[j]);  // row_shr:1
#pragma unroll
    for (int j = 0; j < 7; ++j) agg[j] = dpp_add<0x112, 0xF, true>(agg[j]);  // row_shr:2
#pragma unroll
    for (int j = 0; j < 7; ++j) agg[j] = dpp_add<0x114, 0xF, true>(agg[j]);  // row_shr:4
#pragma unroll
    for (int j = 0; j < 7; ++j) agg[j] = dpp_add<0x118, 0xF, true>(agg[j]);  // row_shr:8
#pragma unroll
    for (int j = 0; j < 7; ++j) agg[j] = dpp_add<0x142, 0xA, false>(agg[j]); // row_bcast15

    float Lex[7];  // exclusive lane prefix
#pragma unroll
    for (int j = 0; j < 7; ++j) Lex[j] = agg[j] - loc[j];

    // object transmittance / weights
    float t_[4], T_[4], w_[4];
    const float TL = __expf(-Lex[0]);
#pragma unroll
    for (int s = 0; s < 4; ++s) t_[s] = __expf(-odd[s]);
    T_[0] = TL;
#pragma unroll
    for (int s = 1; s < 4; ++s) T_[s] = T_[s - 1] * t_[s - 1];
#pragma unroll
    for (int s = 0; s < 4; ++s) w_[s] = (1.0f - t_[s]) * T_[s];

    // partial reductions: [0..2] restored, [3..5] direct, [6..8] backscatter_obj,
    // [9] wsum, [10..12] veil[s=0] broadcast (only lane 0 contributes)
    float red[13];
    red[9] = w_[0] + w_[1] + w_[2] + w_[3];
#pragma unroll
    for (int c = 0; c < 3; ++c) {
        const float BD = Lex[0] + Lex[1 + c];
        const float BB = Lex[0] + Lex[4 + c];
        float sr = 0.0f, sd = 0.0f, sb = 0.0f;
#pragma unroll
        for (int s = 0; s < 4; ++s) {
            const float g = rgbv[3 * s + c];
            const float v = vlv[3 * s + c];
            const float omt = 1.0f - t_[s];
            const float wda = omt * __expf(-(BD + cumO[s] + cumD[4 * c + s]));
            const float wbt = omt * __expf(-(BB + cumO[s] + cumB[4 * c + s]));
            sr += w_[s] * g;
            sd += wda * g;
            sb += (w_[s] - wbt) * v;
        }
        red[c] = sr;
        red[3 + c] = sd;
        red[6 + c] = sb;
        red[10 + c] = (l == 0) ? vlv[c] : 0.0f;
    }

    // butterfly reduction within each 32-lane half — DPP + one ds_swizzle hop
#pragma unroll
    for (int j = 0; j < 13; ++j) red[j] = dpp_add<0xB1, 0xF, false>(red[j]);  // xor1
#pragma unroll
    for (int j = 0; j < 13; ++j) red[j] = dpp_add<0x4E, 0xF, false>(red[j]);  // xor2
#pragma unroll
    for (int j = 0; j < 13; ++j) red[j] = dpp_add<0x141, 0xF, false>(red[j]); // xor4 (half_mirror)
#pragma unroll
    for (int j = 0; j < 13; ++j) red[j] = dpp_add<0x140, 0xF, false>(red[j]); // xor8-equiv (mirror)
#pragma unroll
    for (int j = 0; j < 13; ++j) red[j] = swz16_add(red[j]);                  // xor16

    if (l < 3) {
        const int c = l;
        const float mask = fminf(fmaxf(red[9], 0.0f), 1.0f);
        const float bsr  = red[6 + c] + (1.0f - mask) * red[10 + c];
        const size_t rc = (size_t)r * 3 + c;
        const size_t stride = (size_t)R * 3;
        out[rc]              = fminf(fmaxf(red[3 + c] + bsr, 0.0f), 1.0f); // rgb
        out[stride + rc]     = fminf(fmaxf(red[c],          0.0f), 1.0f); // restored
        out[2 * stride + rc] = fminf(fmaxf(red[3 + c],      0.0f), 1.0f); // direct
        out[3 * stride + rc] = fminf(fmaxf(bsr,             0.0f), 1.0f); // backscatter
    }
}

__global__ __launch_bounds__(256, 2) void uwnerf_render(
    const float* __restrict__ densities,   // [R,S,1]
    const float* __restrict__ rgbs,        // [R,S,3]
    const float* __restrict__ veil,        // [R,S,3]
    const float* __restrict__ dcoef,       // [R,S,3]
    const float* __restrict__ bcoef,       // [R,S,3]
    const float* __restrict__ deltas,      // [R,S,1]
    float* __restrict__ out,               // [4,R,3]: rgb, restored, direct, backscatter
    int R)
{
    const int lane = threadIdx.x & 63;
    const int l = lane & 31;          // lane within ray
    const int r0 = blockIdx.x * 8 + (int)(threadIdx.x >> 6) * 2 + (lane >> 5);
    const int st = (int)gridDim.x * 8;   // rays per sweep
    if (r0 >= R) return;

    const int r1 = r0 + st, r2 = r0 + 2 * st, r3 = r0 + 3 * st;
    // address-safe clamps (for R=65536 these are identities)
    const int a1 = r1 < R ? r1 : 0, a2 = r2 < R ? r2 : 0, a3 = r3 < R ? r3 : 0;

    Ray A, B;

    // prologue: fill both stages
    issue_loads(A, densities, rgbs, veil, dcoef, bcoef, deltas, r0, l);
    issue_loads(B, densities, rgbs, veil, dcoef, bcoef, deltas, a1, l);

    // stage 0: wait for A only (B's 14 loads stay in flight)
    asm volatile("s_waitcnt vmcnt(14)");
    __builtin_amdgcn_sched_barrier(0);
    compute_ray(A, r0, l, out, R);

    // stage 1
    issue_loads(A, densities, rgbs, veil, dcoef, bcoef, deltas, a2, l);
    asm volatile("s_waitcnt vmcnt(14)");
    __builtin_amdgcn_sched_barrier(0);
    if (r1 < R) compute_ray(B, r1, l, out, R);

    // stage 2
    issue_loads(B, densities, rgbs, veil, dcoef, bcoef, deltas, a3, l);
    asm volatile("s_waitcnt vmcnt(14)");
    __builtin_amdgcn_sched_barrier(0);
    if (r2 < R) compute_ray(A, r2, l, out, R);

    // tail: drain everything
    asm volatile("s_waitcnt vmcnt(0)");
    __builtin_amdgcn_sched_barrier(0);
    if (r3 < R) compute_ray(B, r3, l, out, R);
}

extern "C" void kernel_launch(void* const* d_in, const int* in_sizes, int n_in,
                              void* d_out, int out_size, void* d_ws, size_t ws_size,
                              hipStream_t stream) {
    const float* densities = (const float*)d_in[0];
    const float* rgbs      = (const float*)d_in[1];
    const float* veil      = (const float*)d_in[2];
    const float* dcoef     = (const float*)d_in[3];
    const float* bcoef     = (const float*)d_in[4];
    const float* deltas    = (const float*)d_in[5];
    float* out = (float*)d_out;

    const int R = in_sizes[0] / S;   // 65536
    const int blocks = (R + 31) / 32;   // 8 rays/block/sweep * 4 sweeps
    dim3 grid(blocks), block(256);
    uwnerf_render<<<grid, block, 0, stream>>>(densities, rgbs, veil, dcoef, bcoef,
                                              deltas, out, R);
}